// Round 2
// baseline (7732.861 us; speedup 1.0000x reference)
//
#include <hip/hip_runtime.h>
#include <hip/hip_bf16.h>
#include <math.h>

#define BBATCH 256
#define DMODEL 512
#define NHEAD 4
#define DHEAD 128
#define DFFN 1024
#define KCB 8192
#define VEPS 0.02f

typedef __attribute__((ext_vector_type(8))) short short8v;   // 8 bf16 in 4 VGPRs
typedef __attribute__((ext_vector_type(4))) float f32x4;

// ---------------- conv weight transform: wc[(k*512+di)*512 + do] = cw[do][di][k]
__global__ __launch_bounds__(256) void k_wconv(const float* __restrict__ cw,
                                               float* __restrict__ wc) {
    int idx = blockIdx.x * 256 + threadIdx.x;
    if (idx >= 3 * DMODEL * DMODEL) return;
    int dout = idx & (DMODEL - 1);
    int rest = idx >> 9;
    int di = rest & (DMODEL - 1);
    int k = rest >> 9;
    wc[idx] = cw[((size_t)dout * DMODEL + di) * 3 + k];
}

// ---------------- conv GEMM with fused frame gather + exact GELU, fp32 accumulate.
__global__ __launch_bounds__(256) void k_gemm_conv(const float* __restrict__ xin,
                                                   const float* __restrict__ Wc,
                                                   const float* __restrict__ bias,
                                                   float* __restrict__ C,
                                                   int Tin, int Tout) {
    __shared__ __align__(16) float As[16][68];
    __shared__ __align__(16) float Bs[16][68];
    int tid = threadIdx.x;
    int tx = tid & 15, ty = tid >> 4;
    int m0 = blockIdx.y * 64, n0 = blockIdx.x * 64;
    float acc[4][4];
#pragma unroll
    for (int i = 0; i < 4; i++)
#pragma unroll
        for (int j = 0; j < 4; j++) acc[i][j] = 0.0f;

    for (int k0 = 0; k0 < 3 * DMODEL; k0 += 16) {
#pragma unroll
        for (int i = 0; i < 4; i++) {
            int t = tid + i * 256;
            int kk = t & 15, mm = t >> 4;
            int c = k0 + kk;
            int m = m0 + mm;
            int b = m / Tout;
            int tt = m - b * Tout;
            int f = 2 * tt - 2 + (c >> 9);
            if (f < 0) f = 0;
            As[kk][mm] = xin[((size_t)b * Tin + f) * DMODEL + (c & 511)];
            int nn = t & 63, kb = t >> 6;
            Bs[kb][nn] = Wc[(size_t)(k0 + kb) * DMODEL + n0 + nn];
        }
        __syncthreads();
#pragma unroll
        for (int kk = 0; kk < 16; kk++) {
            float4 af = *(const float4*)&As[kk][ty * 4];
            float4 bf = *(const float4*)&Bs[kk][tx * 4];
            float a[4] = {af.x, af.y, af.z, af.w};
            float b[4] = {bf.x, bf.y, bf.z, bf.w};
#pragma unroll
            for (int i = 0; i < 4; i++)
#pragma unroll
                for (int j = 0; j < 4; j++) acc[i][j] = fmaf(a[i], b[j], acc[i][j]);
        }
        __syncthreads();
    }
#pragma unroll
    for (int i = 0; i < 4; i++) {
#pragma unroll
        for (int j = 0; j < 4; j++) {
            double v = (double)acc[i][j] + (double)bias[n0 + tx * 4 + j];
            v = 0.5 * v * (1.0 + erf(v * 0.7071067811865476));
            C[(size_t)(m0 + ty * 4 + i) * DMODEL + n0 + tx * 4 + j] = (float)v;
        }
    }
}

// ---------------- generic GEMM, fp32 accumulate. ACT: 0 none, 2 relu
template <int ACT>
__global__ __launch_bounds__(256) void k_gemm(const float* __restrict__ A, int lda,
                                              const float* __restrict__ Bm, int ldb,
                                              const float* __restrict__ bias,
                                              float* __restrict__ C, int ldc,
                                              int M, int N, int K) {
    __shared__ __align__(16) float As[16][68];
    __shared__ __align__(16) float Bs[16][68];
    int tid = threadIdx.x;
    int tx = tid & 15, ty = tid >> 4;
    int m0 = blockIdx.y * 64, n0 = blockIdx.x * 64;
    float acc[4][4];
#pragma unroll
    for (int i = 0; i < 4; i++)
#pragma unroll
        for (int j = 0; j < 4; j++) acc[i][j] = 0.0f;

    for (int k0 = 0; k0 < K; k0 += 16) {
#pragma unroll
        for (int i = 0; i < 4; i++) {
            int t = tid + i * 256;
            int kk = t & 15, mm = t >> 4;
            As[kk][mm] = A[(size_t)(m0 + mm) * lda + k0 + kk];
            int nn = t & 63, kb = t >> 6;
            Bs[kb][nn] = Bm[(size_t)(k0 + kb) * ldb + n0 + nn];
        }
        __syncthreads();
#pragma unroll
        for (int kk = 0; kk < 16; kk++) {
            float4 af = *(const float4*)&As[kk][ty * 4];
            float4 bf = *(const float4*)&Bs[kk][tx * 4];
            float a[4] = {af.x, af.y, af.z, af.w};
            float b[4] = {bf.x, bf.y, bf.z, bf.w};
#pragma unroll
            for (int i = 0; i < 4; i++)
#pragma unroll
                for (int j = 0; j < 4; j++) acc[i][j] = fmaf(a[i], b[j], acc[i][j]);
        }
        __syncthreads();
    }
#pragma unroll
    for (int i = 0; i < 4; i++) {
#pragma unroll
        for (int j = 0; j < 4; j++) {
            float vv = acc[i][j] + bias[n0 + tx * 4 + j];
            if (ACT == 2) vv = vv > 0.0f ? vv : 0.0f;
            C[(size_t)(m0 + ty * 4 + i) * ldc + n0 + tx * 4 + j] = vv;
        }
    }
}

// ---------------- broadcast helper: uniform lane read
__device__ __forceinline__ float lanebc(float x, int l) {
    return __int_as_float(__builtin_amdgcn_readlane(__float_as_int(x), l));
}

// ---------------- attention: one block per (h, b); 4 waves, rows i%4==wave.
__global__ __launch_bounds__(256) void k_attn(const float* q,
                                              const float* __restrict__ k,
                                              const float* __restrict__ v,
                                              float* out, int T) {
    __shared__ float Ks[98][129];
    int h = blockIdx.x, b = blockIdx.y;
    int tid = threadIdx.x;
    int lane = tid & 63;
    int wave = tid >> 6;
    size_t base = ((size_t)b * T) * DMODEL + (size_t)h * DHEAD;

    for (int idx = tid; idx < T * DHEAD; idx += 256) {
        int j = idx >> 7, d = idx & 127;
        Ks[j][d] = k[base + (size_t)j * DMODEL + d];
    }
    __syncthreads();

    const float SCALE = 0.08838834764831845f;
    for (int i = wave; i < T; i += 4) {
        float qa = q[base + (size_t)i * DMODEL + lane];
        float qb = q[base + (size_t)i * DMODEL + lane + 64];

        int j1 = lane;
        int j2 = lane + 64;
        int j2c = j2 < T ? j2 : 0;
        bool a0 = (j1 <= i);
        bool a1 = (j2 <= i);

        float s0 = 0.0f, s1 = 0.0f;
#pragma unroll 8
        for (int d = 0; d < 64; d++) {
            float qd = lanebc(qa, d);
            s0 = fmaf(qd, Ks[j1][d], s0);
            s1 = fmaf(qd, Ks[j2c][d], s1);
        }
#pragma unroll 8
        for (int d = 0; d < 64; d++) {
            float qd = lanebc(qb, d);
            s0 = fmaf(qd, Ks[j1][64 + d], s0);
            s1 = fmaf(qd, Ks[j2c][64 + d], s1);
        }
        float s0v = a0 ? s0 * SCALE : -1e30f;
        float s1v = a1 ? s1 * SCALE : -1e30f;

        float m = fmaxf(s0v, s1v);
#pragma unroll
        for (int off = 32; off > 0; off >>= 1) m = fmaxf(m, __shfl_xor(m, off, 64));

        float p0 = a0 ? expf(s0v - m) : 0.0f;
        float p1 = a1 ? expf(s1v - m) : 0.0f;

        float sum = p0 + p1;
#pragma unroll
        for (int off = 32; off > 0; off >>= 1) sum += __shfl_xor(sum, off, 64);
        float inv = 1.0f / sum;

        float o0 = 0.0f, o1 = 0.0f;
        int jmax0 = i < 63 ? i : 63;
        for (int j = 0; j <= jmax0; j++) {
            float pj = lanebc(p0, j);
            const float* vr = v + base + (size_t)j * DMODEL;
            o0 = fmaf(pj, vr[lane], o0);
            o1 = fmaf(pj, vr[lane + 64], o1);
        }
        for (int j = 64; j <= i; j++) {
            float pj = lanebc(p1, j - 64);
            const float* vr = v + base + (size_t)j * DMODEL;
            o0 = fmaf(pj, vr[lane], o0);
            o1 = fmaf(pj, vr[lane + 64], o1);
        }
        out[base + (size_t)i * DMODEL + lane] = o0 * inv;
        out[base + (size_t)i * DMODEL + lane + 64] = o1 * inv;
    }
}

// ---------------- fused residual-add + LayerNorm
__global__ __launch_bounds__(128) void k_ln(const float* __restrict__ resid,
                                            const float* __restrict__ y,
                                            const float* __restrict__ g,
                                            const float* __restrict__ bta,
                                            float* __restrict__ out) {
    int row = blockIdx.x;
    int tid = threadIdx.x;
    size_t off = (size_t)row * DMODEL;
    double t[4];
#pragma unroll
    for (int i = 0; i < 4; i++) {
        int d = tid + i * 128;
        t[i] = (double)resid[off + d] + (double)y[off + d];
    }
    __shared__ double rd[2];
    double s = t[0] + t[1] + t[2] + t[3];
#pragma unroll
    for (int o = 32; o > 0; o >>= 1) s += __shfl_down(s, o, 64);
    if ((tid & 63) == 0) rd[tid >> 6] = s;
    __syncthreads();
    double mean = (rd[0] + rd[1]) * (1.0 / 512.0);
    double vs = 0.0;
#pragma unroll
    for (int i = 0; i < 4; i++) { double dl = t[i] - mean; vs += dl * dl; }
    __syncthreads();
#pragma unroll
    for (int o = 32; o > 0; o >>= 1) vs += __shfl_down(vs, o, 64);
    if ((tid & 63) == 0) rd[tid >> 6] = vs;
    __syncthreads();
    double var = (rd[0] + rd[1]) * (1.0 / 512.0);
    double scale = 1.0 / sqrt(var + 1e-5);
#pragma unroll
    for (int i = 0; i < 4; i++) {
        int d = tid + i * 128;
        out[off + d] = (float)((t[i] - mean) * scale * (double)g[d] + (double)bta[d]);
    }
}

// ---------------- codebook squared norms (fp64)
__global__ __launch_bounds__(64) void k_cbn(const float* __restrict__ cb,
                                            double* __restrict__ cbn) {
    int row = blockIdx.x;
    int tid = threadIdx.x;
    const float* r = cb + (size_t)row * DMODEL;
    double s = 0.0;
    for (int d = tid; d < DMODEL; d += 64) { double v = (double)r[d]; s = fma(v, v, s); }
#pragma unroll
    for (int o = 32; o > 0; o >>= 1) s += __shfl_down(s, o, 64);
    if (tid == 0) cbn[row] = s;
}

// ---------------- split fp32 -> (bf16 hi, bf16 lo residual), RNE bit math
__device__ __forceinline__ unsigned short f2bf(float f) {
    unsigned u = __float_as_uint(f);
    unsigned r = (u + 0x7fffu + ((u >> 16) & 1u)) >> 16;
    return (unsigned short)r;
}
__device__ __forceinline__ float bf2f(unsigned short h) {
    return __uint_as_float(((unsigned)h) << 16);
}

__global__ __launch_bounds__(256) void k_split(const float* __restrict__ in,
                                               unsigned short* __restrict__ hi,
                                               unsigned short* __restrict__ lo,
                                               int n4) {
    int i = blockIdx.x * 256 + threadIdx.x;
    if (i >= n4) return;
    float4 v = ((const float4*)in)[i];
    float vv[4] = {v.x, v.y, v.z, v.w};
    unsigned short h[4], l[4];
#pragma unroll
    for (int j = 0; j < 4; j++) {
        h[j] = f2bf(vv[j]);
        l[j] = f2bf(vv[j] - bf2f(h[j]));
    }
    ((ushort4*)hi)[i] = make_ushort4(h[0], h[1], h[2], h[3]);
    ((ushort4*)lo)[i] = make_ushort4(l[0], l[1], l[2], l[3]);
}

// ---------------- VQ phase 1 via split-bf16 MFMA.
// Grid (196, 4): block = 64 rows x 2048 codes. 4 waves; wave w owns rows [16w,16w+16).
// Per wave: 8 accumulators (16 rows x 128 codes); fragments loaded directly from
// global bf16 (16B contiguous along K, L2-resident). dot ~= hi*hi + hi*lo + lo*hi.
__global__ __launch_bounds__(256) void k_vq1m(const unsigned short* __restrict__ xh,
                                              const unsigned short* __restrict__ xl,
                                              const unsigned short* __restrict__ ch,
                                              const unsigned short* __restrict__ cl,
                                              const double* __restrict__ cbn,
                                              float4* __restrict__ cand, int nrows) {
    __shared__ float sD[64][16][2];
    __shared__ int   sI[64][16][2];
    int tid = threadIdx.x;
    int lane = tid & 63, w = tid >> 6;
    int lrow = lane & 15;     // A row feed / B col feed / D col
    int lkg = lane >> 4;      // k-group
    int r0 = blockIdx.x * 64;
    int cbase = blockIdx.y * 2048;

    size_t offA = ((size_t)(r0 + 16 * w + lrow)) * DMODEL + lkg * 8;
    size_t offB = ((size_t)lrow) * DMODEL + lkg * 8;

    float b1[4], b2[4]; int i1[4], i2[4];
#pragma unroll
    for (int v = 0; v < 4; v++) { b1[v] = 1e30f; b2[v] = 1e30f; i1[v] = 0; i2[v] = 0; }

    for (int ci = 0; ci < 16; ci++) {
        int cc = cbase + ci * 128;
        f32x4 acc[8];
#pragma unroll
        for (int s = 0; s < 8; s++) acc[s] = (f32x4){0.0f, 0.0f, 0.0f, 0.0f};

        for (int k0 = 0; k0 < DMODEL; k0 += 32) {
            short8v ah = *(const short8v*)(xh + offA + k0);
            short8v al = *(const short8v*)(xl + offA + k0);
#pragma unroll
            for (int s = 0; s < 8; s++) {
                size_t ob = ((size_t)(cc + s * 16)) * DMODEL + offB + k0;
                short8v bh = *(const short8v*)(ch + ob);
                short8v bl = *(const short8v*)(cl + ob);
                acc[s] = __builtin_amdgcn_mfma_f32_16x16x32_bf16(ah, bh, acc[s], 0, 0, 0);
                acc[s] = __builtin_amdgcn_mfma_f32_16x16x32_bf16(ah, bl, acc[s], 0, 0, 0);
                acc[s] = __builtin_amdgcn_mfma_f32_16x16x32_bf16(al, bh, acc[s], 0, 0, 0);
            }
        }
#pragma unroll
        for (int s = 0; s < 8; s++) {
            int code = cc + s * 16 + lrow;
            float cn = (float)cbn[code];
#pragma unroll
            for (int v = 0; v < 4; v++) {
                float d = cn - 2.0f * acc[s][v];
                if (d < b1[v]) { b2[v] = b1[v]; i2[v] = i1[v]; b1[v] = d; i1[v] = code; }
                else if (d < b2[v]) { b2[v] = d; i2[v] = code; }
            }
        }
    }
    // D row rr = 4*lkg + v within the wave's 16-row tile; 16 lanes (lrow) per row
#pragma unroll
    for (int v = 0; v < 4; v++) {
        int r = 16 * w + 4 * lkg + v;
        sD[r][lrow][0] = b1[v]; sD[r][lrow][1] = b2[v];
        sI[r][lrow][0] = i1[v]; sI[r][lrow][1] = i2[v];
    }
    __syncthreads();
    if (tid < 64) {
        float d1 = 1e30f, d2 = 1e30f; int j1 = 0, j2 = 0;
        for (int t = 0; t < 16; t++) {
#pragma unroll
            for (int e = 0; e < 2; e++) {
                float d = sD[tid][t][e]; int ix = sI[tid][t][e];
                if (d < d1 || (d == d1 && ix < j1)) { d2 = d1; j2 = j1; d1 = d; j1 = ix; }
                else if (d < d2 || (d == d2 && ix < j2)) { d2 = d; j2 = ix; }
            }
        }
        cand[(size_t)blockIdx.y * nrows + r0 + tid] =
            make_float4(d1, __int_as_float(j1), d2, __int_as_float(j2));
    }
}

// ---------------- VQ phase 2: merge 4 splits' top-2; flag near-ties
__global__ __launch_bounds__(256) void k_vq2(const float4* __restrict__ cand,
                                             int* __restrict__ idxbuf,
                                             int* __restrict__ flagbuf, int nrows) {
    int row = blockIdx.x * 256 + threadIdx.x;
    if (row >= nrows) return;
    float d1 = 1e30f, d2 = 1e30f; int j1 = 0, j2 = 0;
#pragma unroll
    for (int s = 0; s < 4; s++) {
        float4 c = cand[(size_t)s * nrows + row];
        float dd[2] = {c.x, c.z};
        int ii[2] = {__float_as_int(c.y), __float_as_int(c.w)};
#pragma unroll
        for (int e = 0; e < 2; e++) {
            float d = dd[e]; int ix = ii[e];
            if (d < d1 || (d == d1 && ix < j1)) { d2 = d1; j2 = j1; d1 = d; j1 = ix; }
            else if (d < d2 || (d == d2 && ix < j2)) { d2 = d; j2 = ix; }
        }
    }
    idxbuf[row] = j1;
    flagbuf[row] = (d2 - d1 < VEPS) ? 1 : 0;
}

// ---------------- VQ phase 3: exact fp64 rescan for flagged rows; write outputs
__global__ __launch_bounds__(256) void k_vq3(const float* __restrict__ x,
                                             const float* __restrict__ cb,
                                             const double* __restrict__ cbn,
                                             const int* __restrict__ idxbuf,
                                             const int* __restrict__ flagbuf,
                                             float* __restrict__ outq,
                                             float* __restrict__ outi) {
    int row = blockIdx.x;
    int tid = threadIdx.x;
    int best = idxbuf[row];
    if (flagbuf[row]) {
        __shared__ float xs[DMODEL];
        __shared__ double sd[256];
        __shared__ int si[256];
        xs[tid] = x[(size_t)row * DMODEL + tid];
        xs[tid + 256] = x[(size_t)row * DMODEL + tid + 256];
        __syncthreads();
        double bd = 1e300; int bi = 0x7fffffff;
        for (int c = tid; c < KCB; c += 256) {
            const float* cr = cb + (size_t)c * DMODEL;
            double dot = 0.0;
#pragma unroll 8
            for (int d = 0; d < DMODEL; d++) dot = fma((double)xs[d], (double)cr[d], dot);
            double dist = cbn[c] - 2.0 * dot;
            if (dist < bd || (dist == bd && c < bi)) { bd = dist; bi = c; }
        }
        sd[tid] = bd; si[tid] = bi;
        __syncthreads();
        for (int off = 128; off > 0; off >>= 1) {
            if (tid < off) {
                if (sd[tid + off] < sd[tid] ||
                    (sd[tid + off] == sd[tid] && si[tid + off] < si[tid])) {
                    sd[tid] = sd[tid + off]; si[tid] = si[tid + off];
                }
            }
            __syncthreads();
        }
        best = si[0];
    }
    const float* crow = cb + (size_t)best * DMODEL;
    outq[(size_t)row * DMODEL + tid] = crow[tid];
    outq[(size_t)row * DMODEL + tid + 256] = crow[tid + 256];
    if (tid == 0) outi[row] = (float)best;
}

extern "C" void kernel_launch(void* const* d_in, const int* in_sizes, int n_in,
                              void* d_out, int out_size, void* d_ws, size_t ws_size,
                              hipStream_t stream) {
    const float* motion = (const float*)d_in[0];
    const float* conv_w = (const float*)d_in[1];
    const float* conv_b = (const float*)d_in[2];
    const float* wqkv   = (const float*)d_in[3];
    const float* bqkv   = (const float*)d_in[4];
    const float* wo     = (const float*)d_in[5];
    const float* bo     = (const float*)d_in[6];
    const float* ln1g   = (const float*)d_in[7];
    const float* ln1b   = (const float*)d_in[8];
    const float* ln2g   = (const float*)d_in[9];
    const float* ln2b   = (const float*)d_in[10];
    const float* w1     = (const float*)d_in[11];
    const float* b1     = (const float*)d_in[12];
    const float* w2     = (const float*)d_in[13];
    const float* b2     = (const float*)d_in[14];
    const float* cb     = (const float*)d_in[15];

    const size_t SZc = (size_t)25088 * DMODEL;
    float* wsf = (float*)d_ws;
    float*  S0  = wsf + 0 * SZc;
    float*  S1  = wsf + 1 * SZc;
    float*  S2  = wsf + 2 * SZc;
    float*  S3  = wsf + 3 * SZc;
    float*  Wc  = wsf + 4 * SZc;
    char* p = (char*)(Wc + 2 * 3 * DMODEL * DMODEL);
    double* cbn   = (double*)p;            p += KCB * 8;
    float4* cand  = (float4*)p;            p += (size_t)4 * 12544 * 16;
    int*   idxbuf = (int*)p;               p += 12544 * 4;
    int*   flagbuf= (int*)p;

    k_cbn<<<dim3(KCB), dim3(64), 0, stream>>>(cb, cbn);
    k_wconv<<<dim3(3072), dim3(256), 0, stream>>>(conv_w, Wc);
    k_wconv<<<dim3(3072), dim3(256), 0, stream>>>(conv_w + (size_t)3 * DMODEL * DMODEL,
                                                  Wc + (size_t)3 * DMODEL * DMODEL);

    const float* xin = motion;
    int Tin = 196;
    for (int l = 0; l < 2; l++) {
        int Tout = Tin / 2;            // 98, then 49
        int M = BBATCH * Tout;         // 25088, then 12544
        const float* wq = wqkv + (size_t)l * DMODEL * 3 * DMODEL;
        const float* bq = bqkv + (size_t)l * 3 * DMODEL;
        const float* WcL = Wc + (size_t)l * 3 * DMODEL * DMODEL;

        k_gemm_conv<<<dim3(DMODEL / 64, M / 64), dim3(256), 0, stream>>>(
            xin, WcL, conv_b + l * DMODEL, S0, Tin, Tout);
        float* qkvdst[3] = {S1, S2, S3};
        for (int s = 0; s < 3; s++) {
            k_gemm<0><<<dim3(DMODEL / 64, M / 64), dim3(256), 0, stream>>>(
                S0, DMODEL, wq + s * DMODEL, 3 * DMODEL, bq + s * DMODEL,
                qkvdst[s], DMODEL, M, DMODEL, DMODEL);
        }
        k_attn<<<dim3(NHEAD, BBATCH), dim3(256), 0, stream>>>(S1, S2, S3, S1, Tout);
        k_gemm<0><<<dim3(DMODEL / 64, M / 64), dim3(256), 0, stream>>>(
            S1, DMODEL, wo + (size_t)l * DMODEL * DMODEL, DMODEL, bo + l * DMODEL,
            S2, DMODEL, M, DMODEL, DMODEL);
        k_ln<<<dim3(M), dim3(128), 0, stream>>>(S0, S2, ln1g + l * DMODEL, ln1b + l * DMODEL, S3);
        k_gemm<2><<<dim3(DFFN / 64, M / 64), dim3(256), 0, stream>>>(
            S3, DMODEL, w1 + (size_t)l * DMODEL * DFFN, DFFN, b1 + l * DFFN,
            S1, DFFN, M, DFFN, DMODEL);
        k_gemm<0><<<dim3(DMODEL / 64, M / 64), dim3(256), 0, stream>>>(
            S1, DFFN, w2 + (size_t)l * DFFN * DMODEL, DMODEL, b2 + l * DMODEL,
            S0, DMODEL, M, DMODEL, DFFN);
        k_ln<<<dim3(M), dim3(128), 0, stream>>>(S3, S0, ln2g + l * DMODEL, ln2b + l * DMODEL, S1);

        xin = S1;
        Tin = Tout;
    }

    // ---- VQ: split x (S1) and codebook to bf16 hi/lo in freed scratch (S2, S3)
    unsigned short* xh = (unsigned short*)S2;
    unsigned short* xl = xh + (size_t)12544 * DMODEL;
    unsigned short* chb = (unsigned short*)S3;
    unsigned short* clb = chb + (size_t)KCB * DMODEL;
    k_split<<<dim3(12544 * DMODEL / 4 / 256), dim3(256), 0, stream>>>(S1, xh, xl,
                                                                      12544 * DMODEL / 4);
    k_split<<<dim3(KCB * DMODEL / 4 / 256), dim3(256), 0, stream>>>(cb, chb, clb,
                                                                    KCB * DMODEL / 4);

    float* outq = (float*)d_out;
    float* outi = outq + (size_t)12544 * DMODEL;
    k_vq1m<<<dim3(12544 / 64, 4), dim3(256), 0, stream>>>(xh, xl, chb, clb, cbn, cand, 12544);
    k_vq2<<<dim3(49), dim3(256), 0, stream>>>(cand, idxbuf, flagbuf, 12544);
    k_vq3<<<dim3(12544), dim3(256), 0, stream>>>(S1, cb, cbn, idxbuf, flagbuf, outq, outi);
}

// Round 3
// 5341.418 us; speedup vs baseline: 1.4477x; 1.4477x over previous
//
#include <hip/hip_runtime.h>
#include <hip/hip_bf16.h>
#include <math.h>

#define BBATCH 256
#define DMODEL 512
#define NHEAD 4
#define DHEAD 128
#define DFFN 1024
#define KCB 8192
#define VEPS 0.02f
#define NROWS 12544
#define NSPLIT 64   // 8192 / 128 code tiles

typedef __attribute__((ext_vector_type(8))) short short8v;   // 8 bf16 in 4 VGPRs
typedef __attribute__((ext_vector_type(4))) float f32x4;

// ---------------- conv weight transform: wc[(k*512+di)*512 + do] = cw[do][di][k]
__global__ __launch_bounds__(256) void k_wconv(const float* __restrict__ cw,
                                               float* __restrict__ wc) {
    int idx = blockIdx.x * 256 + threadIdx.x;
    if (idx >= 3 * DMODEL * DMODEL) return;
    int dout = idx & (DMODEL - 1);
    int rest = idx >> 9;
    int di = rest & (DMODEL - 1);
    int k = rest >> 9;
    wc[idx] = cw[((size_t)dout * DMODEL + di) * 3 + k];
}

// ---------------- conv GEMM with fused frame gather + exact GELU, fp32 accumulate.
__global__ __launch_bounds__(256) void k_gemm_conv(const float* __restrict__ xin,
                                                   const float* __restrict__ Wc,
                                                   const float* __restrict__ bias,
                                                   float* __restrict__ C,
                                                   int Tin, int Tout) {
    __shared__ __align__(16) float As[16][68];
    __shared__ __align__(16) float Bs[16][68];
    int tid = threadIdx.x;
    int tx = tid & 15, ty = tid >> 4;
    int m0 = blockIdx.y * 64, n0 = blockIdx.x * 64;
    float acc[4][4];
#pragma unroll
    for (int i = 0; i < 4; i++)
#pragma unroll
        for (int j = 0; j < 4; j++) acc[i][j] = 0.0f;

    for (int k0 = 0; k0 < 3 * DMODEL; k0 += 16) {
#pragma unroll
        for (int i = 0; i < 4; i++) {
            int t = tid + i * 256;
            int kk = t & 15, mm = t >> 4;
            int c = k0 + kk;
            int m = m0 + mm;
            int b = m / Tout;
            int tt = m - b * Tout;
            int f = 2 * tt - 2 + (c >> 9);
            if (f < 0) f = 0;
            As[kk][mm] = xin[((size_t)b * Tin + f) * DMODEL + (c & 511)];
            int nn = t & 63, kb = t >> 6;
            Bs[kb][nn] = Wc[(size_t)(k0 + kb) * DMODEL + n0 + nn];
        }
        __syncthreads();
#pragma unroll
        for (int kk = 0; kk < 16; kk++) {
            float4 af = *(const float4*)&As[kk][ty * 4];
            float4 bf = *(const float4*)&Bs[kk][tx * 4];
            float a[4] = {af.x, af.y, af.z, af.w};
            float b[4] = {bf.x, bf.y, bf.z, bf.w};
#pragma unroll
            for (int i = 0; i < 4; i++)
#pragma unroll
                for (int j = 0; j < 4; j++) acc[i][j] = fmaf(a[i], b[j], acc[i][j]);
        }
        __syncthreads();
    }
#pragma unroll
    for (int i = 0; i < 4; i++) {
#pragma unroll
        for (int j = 0; j < 4; j++) {
            double v = (double)acc[i][j] + (double)bias[n0 + tx * 4 + j];
            v = 0.5 * v * (1.0 + erf(v * 0.7071067811865476));
            C[(size_t)(m0 + ty * 4 + i) * DMODEL + n0 + tx * 4 + j] = (float)v;
        }
    }
}

// ---------------- generic GEMM, fp32 accumulate. ACT: 0 none, 2 relu
template <int ACT>
__global__ __launch_bounds__(256) void k_gemm(const float* __restrict__ A, int lda,
                                              const float* __restrict__ Bm, int ldb,
                                              const float* __restrict__ bias,
                                              float* __restrict__ C, int ldc,
                                              int M, int N, int K) {
    __shared__ __align__(16) float As[16][68];
    __shared__ __align__(16) float Bs[16][68];
    int tid = threadIdx.x;
    int tx = tid & 15, ty = tid >> 4;
    int m0 = blockIdx.y * 64, n0 = blockIdx.x * 64;
    float acc[4][4];
#pragma unroll
    for (int i = 0; i < 4; i++)
#pragma unroll
        for (int j = 0; j < 4; j++) acc[i][j] = 0.0f;

    for (int k0 = 0; k0 < K; k0 += 16) {
#pragma unroll
        for (int i = 0; i < 4; i++) {
            int t = tid + i * 256;
            int kk = t & 15, mm = t >> 4;
            As[kk][mm] = A[(size_t)(m0 + mm) * lda + k0 + kk];
            int nn = t & 63, kb = t >> 6;
            Bs[kb][nn] = Bm[(size_t)(k0 + kb) * ldb + n0 + nn];
        }
        __syncthreads();
#pragma unroll
        for (int kk = 0; kk < 16; kk++) {
            float4 af = *(const float4*)&As[kk][ty * 4];
            float4 bf = *(const float4*)&Bs[kk][tx * 4];
            float a[4] = {af.x, af.y, af.z, af.w};
            float b[4] = {bf.x, bf.y, bf.z, bf.w};
#pragma unroll
            for (int i = 0; i < 4; i++)
#pragma unroll
                for (int j = 0; j < 4; j++) acc[i][j] = fmaf(a[i], b[j], acc[i][j]);
        }
        __syncthreads();
    }
#pragma unroll
    for (int i = 0; i < 4; i++) {
#pragma unroll
        for (int j = 0; j < 4; j++) {
            float vv = acc[i][j] + bias[n0 + tx * 4 + j];
            if (ACT == 2) vv = vv > 0.0f ? vv : 0.0f;
            C[(size_t)(m0 + ty * 4 + i) * ldc + n0 + tx * 4 + j] = vv;
        }
    }
}

// ---------------- broadcast helper: uniform lane read
__device__ __forceinline__ float lanebc(float x, int l) {
    return __int_as_float(__builtin_amdgcn_readlane(__float_as_int(x), l));
}

// ---------------- attention: one block per (h, b); 4 waves, rows i%4==wave.
__global__ __launch_bounds__(256) void k_attn(const float* q,
                                              const float* __restrict__ k,
                                              const float* __restrict__ v,
                                              float* out, int T) {
    __shared__ float Ks[98][129];
    int h = blockIdx.x, b = blockIdx.y;
    int tid = threadIdx.x;
    int lane = tid & 63;
    int wave = tid >> 6;
    size_t base = ((size_t)b * T) * DMODEL + (size_t)h * DHEAD;

    for (int idx = tid; idx < T * DHEAD; idx += 256) {
        int j = idx >> 7, d = idx & 127;
        Ks[j][d] = k[base + (size_t)j * DMODEL + d];
    }
    __syncthreads();

    const float SCALE = 0.08838834764831845f;
    for (int i = wave; i < T; i += 4) {
        float qa = q[base + (size_t)i * DMODEL + lane];
        float qb = q[base + (size_t)i * DMODEL + lane + 64];

        int j1 = lane;
        int j2 = lane + 64;
        int j2c = j2 < T ? j2 : 0;
        bool a0 = (j1 <= i);
        bool a1 = (j2 <= i);

        float s0 = 0.0f, s1 = 0.0f;
#pragma unroll 8
        for (int d = 0; d < 64; d++) {
            float qd = lanebc(qa, d);
            s0 = fmaf(qd, Ks[j1][d], s0);
            s1 = fmaf(qd, Ks[j2c][d], s1);
        }
#pragma unroll 8
        for (int d = 0; d < 64; d++) {
            float qd = lanebc(qb, d);
            s0 = fmaf(qd, Ks[j1][64 + d], s0);
            s1 = fmaf(qd, Ks[j2c][64 + d], s1);
        }
        float s0v = a0 ? s0 * SCALE : -1e30f;
        float s1v = a1 ? s1 * SCALE : -1e30f;

        float m = fmaxf(s0v, s1v);
#pragma unroll
        for (int off = 32; off > 0; off >>= 1) m = fmaxf(m, __shfl_xor(m, off, 64));

        float p0 = a0 ? expf(s0v - m) : 0.0f;
        float p1 = a1 ? expf(s1v - m) : 0.0f;

        float sum = p0 + p1;
#pragma unroll
        for (int off = 32; off > 0; off >>= 1) sum += __shfl_xor(sum, off, 64);
        float inv = 1.0f / sum;

        float o0 = 0.0f, o1 = 0.0f;
        int jmax0 = i < 63 ? i : 63;
        for (int j = 0; j <= jmax0; j++) {
            float pj = lanebc(p0, j);
            const float* vr = v + base + (size_t)j * DMODEL;
            o0 = fmaf(pj, vr[lane], o0);
            o1 = fmaf(pj, vr[lane + 64], o1);
        }
        for (int j = 64; j <= i; j++) {
            float pj = lanebc(p1, j - 64);
            const float* vr = v + base + (size_t)j * DMODEL;
            o0 = fmaf(pj, vr[lane], o0);
            o1 = fmaf(pj, vr[lane + 64], o1);
        }
        out[base + (size_t)i * DMODEL + lane] = o0 * inv;
        out[base + (size_t)i * DMODEL + lane + 64] = o1 * inv;
    }
}

// ---------------- fused residual-add + LayerNorm
__global__ __launch_bounds__(128) void k_ln(const float* __restrict__ resid,
                                            const float* __restrict__ y,
                                            const float* __restrict__ g,
                                            const float* __restrict__ bta,
                                            float* __restrict__ out) {
    int row = blockIdx.x;
    int tid = threadIdx.x;
    size_t off = (size_t)row * DMODEL;
    double t[4];
#pragma unroll
    for (int i = 0; i < 4; i++) {
        int d = tid + i * 128;
        t[i] = (double)resid[off + d] + (double)y[off + d];
    }
    __shared__ double rd[2];
    double s = t[0] + t[1] + t[2] + t[3];
#pragma unroll
    for (int o = 32; o > 0; o >>= 1) s += __shfl_down(s, o, 64);
    if ((tid & 63) == 0) rd[tid >> 6] = s;
    __syncthreads();
    double mean = (rd[0] + rd[1]) * (1.0 / 512.0);
    double vs = 0.0;
#pragma unroll
    for (int i = 0; i < 4; i++) { double dl = t[i] - mean; vs += dl * dl; }
    __syncthreads();
#pragma unroll
    for (int o = 32; o > 0; o >>= 1) vs += __shfl_down(vs, o, 64);
    if ((tid & 63) == 0) rd[tid >> 6] = vs;
    __syncthreads();
    double var = (rd[0] + rd[1]) * (1.0 / 512.0);
    double scale = 1.0 / sqrt(var + 1e-5);
#pragma unroll
    for (int i = 0; i < 4; i++) {
        int d = tid + i * 128;
        out[off + d] = (float)((t[i] - mean) * scale * (double)g[d] + (double)bta[d]);
    }
}

// ---------------- codebook squared norms (fp64)
__global__ __launch_bounds__(64) void k_cbn(const float* __restrict__ cb,
                                            double* __restrict__ cbn) {
    int row = blockIdx.x;
    int tid = threadIdx.x;
    const float* r = cb + (size_t)row * DMODEL;
    double s = 0.0;
    for (int d = tid; d < DMODEL; d += 64) { double v = (double)r[d]; s = fma(v, v, s); }
#pragma unroll
    for (int o = 32; o > 0; o >>= 1) s += __shfl_down(s, o, 64);
    if (tid == 0) cbn[row] = s;
}

// ---------------- split fp32 -> (bf16 hi, bf16 lo residual), RNE bit math
__device__ __forceinline__ unsigned short f2bf(float f) {
    unsigned u = __float_as_uint(f);
    unsigned r = (u + 0x7fffu + ((u >> 16) & 1u)) >> 16;
    return (unsigned short)r;
}
__device__ __forceinline__ float bf2f(unsigned short h) {
    return __uint_as_float(((unsigned)h) << 16);
}

__global__ __launch_bounds__(256) void k_split(const float* __restrict__ in,
                                               unsigned short* __restrict__ hi,
                                               unsigned short* __restrict__ lo,
                                               int n4) {
    int i = blockIdx.x * 256 + threadIdx.x;
    if (i >= n4) return;
    float4 v = ((const float4*)in)[i];
    float vv[4] = {v.x, v.y, v.z, v.w};
    unsigned short h[4], l[4];
#pragma unroll
    for (int j = 0; j < 4; j++) {
        h[j] = f2bf(vv[j]);
        l[j] = f2bf(vv[j] - bf2f(h[j]));
    }
    ((ushort4*)hi)[i] = make_ushort4(h[0], h[1], h[2], h[3]);
    ((ushort4*)lo)[i] = make_ushort4(l[0], l[1], l[2], l[3]);
}

// ---------------- VQ phase 1: split-bf16 MFMA GEMM, LDS-staged (m97-style).
// Grid: 6272 blocks (XCD-swizzled) = 64 code-tiles x 98 row-tiles, 128x128 per block.
// BK=64; LDS holds Ah/Al/Bh/Bl tiles (64 KB), XOR-swizzled (seg ^= row&7) on write+read.
// 4 waves in 2x2 grid, each 64x64 (4x4 accs). dot ~= hi*hi + hi*lo + lo*hi.
// Epilogue: per-lane top2-of-4 -> LDS merge (reuses staging LDS) -> cand[64][NROWS].
__global__ __launch_bounds__(256) void k_vq1m(const unsigned short* __restrict__ xh,
                                              const unsigned short* __restrict__ xl,
                                              const unsigned short* __restrict__ ch,
                                              const unsigned short* __restrict__ cl,
                                              const double* __restrict__ cbn,
                                              float4* __restrict__ cand) {
    __shared__ __align__(16) unsigned char smem[65536];
    unsigned short* AhU = (unsigned short*)smem;           // [128][64]
    unsigned short* AlU = AhU + 8192;
    unsigned short* BhU = AlU + 8192;
    unsigned short* BlU = BhU + 8192;

    int tid = threadIdx.x;
    int lane = tid & 63, wave = tid >> 6;
    int lrow = lane & 15;          // fragment row/col feed; D col
    int lkg = lane >> 4;           // k-group; D row block
    int wr = wave >> 1, wc = wave & 1;
    int wrbase = wr * 64, wcbase = wc * 64;

    // bijective XCD swizzle (6272 % 8 == 0): same code-tile groups on same XCD
    int wg = (blockIdx.x & 7) * (6272 / 8) + (blockIdx.x >> 3);
    int bx = wg / 98;              // code tile 0..63
    int by = wg % 98;              // row tile 0..97
    int r0 = by * 128, c0 = bx * 128;

    const int srow = tid >> 3;     // 0..31
    const int seg = tid & 7;
    const int sw = seg ^ (srow & 7);   // swizzled seg (row&7 == srow&7 for all rounds)

    f32x4 acc[4][4];
#pragma unroll
    for (int m = 0; m < 4; m++)
#pragma unroll
        for (int n = 0; n < 4; n++) acc[m][n] = (f32x4){0.0f, 0.0f, 0.0f, 0.0f};

    for (int ks = 0; ks < 8; ks++) {
        int k0 = ks * 64;
        // ---- stage: 4 arrays x 4 rounds; 16B per thread per round
#pragma unroll
        for (int rd = 0; rd < 4; rd++) {
            int row = rd * 32 + srow;
            size_t ga = (((size_t)(r0 + row)) << 9) + k0 + seg * 8;
            size_t gb = (((size_t)(c0 + row)) << 9) + k0 + seg * 8;
            int la = row * 64 + sw * 8;
            *(short8v*)(AhU + la) = *(const short8v*)(xh + ga);
            *(short8v*)(AlU + la) = *(const short8v*)(xl + ga);
            *(short8v*)(BhU + la) = *(const short8v*)(ch + gb);
            *(short8v*)(BlU + la) = *(const short8v*)(cl + gb);
        }
        __syncthreads();
        // ---- compute: 2 k-subtiles of 32
#pragma unroll
        for (int ksub = 0; ksub < 2; ksub++) {
            int segsw = ((ksub * 4 + lkg) ^ (lrow & 7)) * 8;
            short8v afh[4], afl[4], bfh[4], bfl[4];
#pragma unroll
            for (int m = 0; m < 4; m++) {
                int off = (wrbase + m * 16 + lrow) * 64 + segsw;
                afh[m] = *(const short8v*)(AhU + off);
                afl[m] = *(const short8v*)(AlU + off);
            }
#pragma unroll
            for (int n = 0; n < 4; n++) {
                int off = (wcbase + n * 16 + lrow) * 64 + segsw;
                bfh[n] = *(const short8v*)(BhU + off);
                bfl[n] = *(const short8v*)(BlU + off);
            }
#pragma unroll
            for (int m = 0; m < 4; m++)
#pragma unroll
                for (int n = 0; n < 4; n++) {
                    acc[m][n] = __builtin_amdgcn_mfma_f32_16x16x32_bf16(afh[m], bfh[n], acc[m][n], 0, 0, 0);
                    acc[m][n] = __builtin_amdgcn_mfma_f32_16x16x32_bf16(afh[m], bfl[n], acc[m][n], 0, 0, 0);
                    acc[m][n] = __builtin_amdgcn_mfma_f32_16x16x32_bf16(afl[m], bfh[n], acc[m][n], 0, 0, 0);
                }
        }
        __syncthreads();
    }

    // ---- epilogue: distances + top-2. Reuse smem as sD[128][64] / sI[128][64].
    float cnv[4];
#pragma unroll
    for (int n = 0; n < 4; n++) cnv[n] = (float)cbn[c0 + wcbase + n * 16 + lrow];

    float* sD = (float*)smem;
    int* sI = (int*)(smem + 32768);
#pragma unroll
    for (int m = 0; m < 4; m++)
#pragma unroll
        for (int v = 0; v < 4; v++) {
            int row = wrbase + m * 16 + lkg * 4 + v;
            float d1 = 1e30f, d2 = 1e30f; int j1 = 0, j2 = 0;
#pragma unroll
            for (int n = 0; n < 4; n++) {
                int code = c0 + wcbase + n * 16 + lrow;
                float d = cnv[n] - 2.0f * acc[m][n][v];
                if (d < d1 || (d == d1 && code < j1)) { d2 = d1; j2 = j1; d1 = d; j1 = code; }
                else if (d < d2 || (d == d2 && code < j2)) { d2 = d; j2 = code; }
            }
            int slot = (wc * 16 + lrow) * 2;
            sD[row * 64 + slot] = d1; sD[row * 64 + slot + 1] = d2;
            sI[row * 64 + slot] = j1; sI[row * 64 + slot + 1] = j2;
        }
    __syncthreads();
    if (tid < 128) {
        float d1 = 1e30f, d2 = 1e30f; int j1 = 0, j2 = 0;
        for (int e = 0; e < 64; e++) {
            float d = sD[tid * 64 + e]; int ix = sI[tid * 64 + e];
            if (d < d1 || (d == d1 && ix < j1)) { d2 = d1; j2 = j1; d1 = d; j1 = ix; }
            else if (d < d2 || (d == d2 && ix < j2)) { d2 = d; j2 = ix; }
        }
        cand[(size_t)bx * NROWS + r0 + tid] =
            make_float4(d1, __int_as_float(j1), d2, __int_as_float(j2));
    }
}

// ---------------- VQ phase 2: merge 64 splits' top-2; flag near-ties
__global__ __launch_bounds__(256) void k_vq2(const float4* __restrict__ cand,
                                             int* __restrict__ idxbuf,
                                             int* __restrict__ flagbuf, int nrows) {
    int row = blockIdx.x * 256 + threadIdx.x;
    if (row >= nrows) return;
    float d1 = 1e30f, d2 = 1e30f; int j1 = 0, j2 = 0;
    for (int s = 0; s < NSPLIT; s++) {
        float4 c = cand[(size_t)s * nrows + row];
        float dd[2] = {c.x, c.z};
        int ii[2] = {__float_as_int(c.y), __float_as_int(c.w)};
#pragma unroll
        for (int e = 0; e < 2; e++) {
            float d = dd[e]; int ix = ii[e];
            if (d < d1 || (d == d1 && ix < j1)) { d2 = d1; j2 = j1; d1 = d; j1 = ix; }
            else if (d < d2 || (d == d2 && ix < j2)) { d2 = d; j2 = ix; }
        }
    }
    idxbuf[row] = j1;
    flagbuf[row] = (d2 - d1 < VEPS) ? 1 : 0;
}

// ---------------- VQ phase 3: exact fp64 rescan for flagged rows; write outputs
__global__ __launch_bounds__(256) void k_vq3(const float* __restrict__ x,
                                             const float* __restrict__ cb,
                                             const double* __restrict__ cbn,
                                             const int* __restrict__ idxbuf,
                                             const int* __restrict__ flagbuf,
                                             float* __restrict__ outq,
                                             float* __restrict__ outi) {
    int row = blockIdx.x;
    int tid = threadIdx.x;
    int best = idxbuf[row];
    if (flagbuf[row]) {
        __shared__ float xs[DMODEL];
        __shared__ double sd[256];
        __shared__ int si[256];
        xs[tid] = x[(size_t)row * DMODEL + tid];
        xs[tid + 256] = x[(size_t)row * DMODEL + tid + 256];
        __syncthreads();
        double bd = 1e300; int bi = 0x7fffffff;
        for (int c = tid; c < KCB; c += 256) {
            const float* cr = cb + (size_t)c * DMODEL;
            double dot = 0.0;
#pragma unroll 8
            for (int d = 0; d < DMODEL; d++) dot = fma((double)xs[d], (double)cr[d], dot);
            double dist = cbn[c] - 2.0 * dot;
            if (dist < bd || (dist == bd && c < bi)) { bd = dist; bi = c; }
        }
        sd[tid] = bd; si[tid] = bi;
        __syncthreads();
        for (int off = 128; off > 0; off >>= 1) {
            if (tid < off) {
                if (sd[tid + off] < sd[tid] ||
                    (sd[tid + off] == sd[tid] && si[tid + off] < si[tid])) {
                    sd[tid] = sd[tid + off]; si[tid] = si[tid + off];
                }
            }
            __syncthreads();
        }
        best = si[0];
    }
    const float* crow = cb + (size_t)best * DMODEL;
    outq[(size_t)row * DMODEL + tid] = crow[tid];
    outq[(size_t)row * DMODEL + tid + 256] = crow[tid + 256];
    if (tid == 0) outi[row] = (float)best;
}

extern "C" void kernel_launch(void* const* d_in, const int* in_sizes, int n_in,
                              void* d_out, int out_size, void* d_ws, size_t ws_size,
                              hipStream_t stream) {
    const float* motion = (const float*)d_in[0];
    const float* conv_w = (const float*)d_in[1];
    const float* conv_b = (const float*)d_in[2];
    const float* wqkv   = (const float*)d_in[3];
    const float* bqkv   = (const float*)d_in[4];
    const float* wo     = (const float*)d_in[5];
    const float* bo     = (const float*)d_in[6];
    const float* ln1g   = (const float*)d_in[7];
    const float* ln1b   = (const float*)d_in[8];
    const float* ln2g   = (const float*)d_in[9];
    const float* ln2b   = (const float*)d_in[10];
    const float* w1     = (const float*)d_in[11];
    const float* b1     = (const float*)d_in[12];
    const float* w2     = (const float*)d_in[13];
    const float* b2     = (const float*)d_in[14];
    const float* cb     = (const float*)d_in[15];

    const size_t SZc = (size_t)25088 * DMODEL;
    float* wsf = (float*)d_ws;
    float*  S0  = wsf + 0 * SZc;
    float*  S1  = wsf + 1 * SZc;
    float*  S2  = wsf + 2 * SZc;
    float*  S3  = wsf + 3 * SZc;
    float*  Wc  = wsf + 4 * SZc;
    char* p = (char*)(Wc + 2 * 3 * DMODEL * DMODEL);
    double* cbn   = (double*)p;            p += KCB * 8;
    int*   idxbuf = (int*)p;               p += NROWS * 4;
    int*   flagbuf= (int*)p;

    k_cbn<<<dim3(KCB), dim3(64), 0, stream>>>(cb, cbn);
    k_wconv<<<dim3(3072), dim3(256), 0, stream>>>(conv_w, Wc);
    k_wconv<<<dim3(3072), dim3(256), 0, stream>>>(conv_w + (size_t)3 * DMODEL * DMODEL,
                                                  Wc + (size_t)3 * DMODEL * DMODEL);

    const float* xin = motion;
    int Tin = 196;
    for (int l = 0; l < 2; l++) {
        int Tout = Tin / 2;            // 98, then 49
        int M = BBATCH * Tout;         // 25088, then 12544
        const float* wq = wqkv + (size_t)l * DMODEL * 3 * DMODEL;
        const float* bq = bqkv + (size_t)l * 3 * DMODEL;
        const float* WcL = Wc + (size_t)l * 3 * DMODEL * DMODEL;

        k_gemm_conv<<<dim3(DMODEL / 64, M / 64), dim3(256), 0, stream>>>(
            xin, WcL, conv_b + l * DMODEL, S0, Tin, Tout);
        float* qkvdst[3] = {S1, S2, S3};
        for (int s = 0; s < 3; s++) {
            k_gemm<0><<<dim3(DMODEL / 64, M / 64), dim3(256), 0, stream>>>(
                S0, DMODEL, wq + s * DMODEL, 3 * DMODEL, bq + s * DMODEL,
                qkvdst[s], DMODEL, M, DMODEL, DMODEL);
        }
        k_attn<<<dim3(NHEAD, BBATCH), dim3(256), 0, stream>>>(S1, S2, S3, S1, Tout);
        k_gemm<0><<<dim3(DMODEL / 64, M / 64), dim3(256), 0, stream>>>(
            S1, DMODEL, wo + (size_t)l * DMODEL * DMODEL, DMODEL, bo + l * DMODEL,
            S2, DMODEL, M, DMODEL, DMODEL);
        k_ln<<<dim3(M), dim3(128), 0, stream>>>(S0, S2, ln1g + l * DMODEL, ln1b + l * DMODEL, S3);
        k_gemm<2><<<dim3(DFFN / 64, M / 64), dim3(256), 0, stream>>>(
            S3, DMODEL, w1 + (size_t)l * DMODEL * DFFN, DFFN, b1 + l * DFFN,
            S1, DFFN, M, DFFN, DMODEL);
        k_gemm<0><<<dim3(DMODEL / 64, M / 64), dim3(256), 0, stream>>>(
            S1, DFFN, w2 + (size_t)l * DFFN * DMODEL, DMODEL, b2 + l * DMODEL,
            S0, DMODEL, M, DMODEL, DFFN);
        k_ln<<<dim3(M), dim3(128), 0, stream>>>(S3, S0, ln2g + l * DMODEL, ln2b + l * DMODEL, S1);

        xin = S1;
        Tin = Tout;
    }

    // ---- VQ: split x (S1) and codebook to bf16 hi/lo in freed scratch (S2, S3).
    // cand (64 splits x NROWS float4 = 12.85 MB) lives in freed S0.
    unsigned short* xh = (unsigned short*)S2;
    unsigned short* xl = xh + (size_t)NROWS * DMODEL;
    unsigned short* chb = (unsigned short*)S3;
    unsigned short* clb = chb + (size_t)KCB * DMODEL;
    float4* cand = (float4*)S0;
    k_split<<<dim3(NROWS * DMODEL / 4 / 256), dim3(256), 0, stream>>>(S1, xh, xl,
                                                                      NROWS * DMODEL / 4);
    k_split<<<dim3(KCB * DMODEL / 4 / 256), dim3(256), 0, stream>>>(cb, chb, clb,
                                                                    KCB * DMODEL / 4);

    float* outq = (float*)d_out;
    float* outi = outq + (size_t)NROWS * DMODEL;
    k_vq1m<<<dim3(98 * NSPLIT), dim3(256), 0, stream>>>(xh, xl, chb, clb, cbn, cand);
    k_vq2<<<dim3(49), dim3(256), 0, stream>>>(cand, idxbuf, flagbuf, NROWS);
    k_vq3<<<dim3(NROWS), dim3(256), 0, stream>>>(S1, cb, cbn, idxbuf, flagbuf, outq, outi);
}